// Round 5
// baseline (112.148 us; speedup 1.0000x reference)
//
#include <hip/hip_runtime.h>

// Quantizer_189: 1-D VQ codebook lookup. x: [16,1,512,512] fp32 (N=4,194,304
// scalars; C=D=1 so transposes are no-ops), weight: [128,1].
//
// Reference model (NumPy fp32, per-op rounding, NO fma — verified rounds 3/4,
// absmax == 0.0):
//   dist_k = fl( fl( fl(x*x) + fl(w_k*w_k) ) - fl( fl(2x) * w_k ) )
//   idx    = np.argmin(dist) — first ORIGINAL index wins ties
//   out    = w[idx]
//
// Round-5: LDS-pipe was the bottleneck (~16 us of ~30). Changes:
//  - window reads are b32 (sorted w only); w^2 recomputed in VALU with the
//    same rounding (wv*wv, contraction blocked) -> halves window LDS bytes.
//  - search level-8 moved to a register cndmask tree (15 uniform values in
//    regs); only 3 LDS search reads (steps 4,2,1) remain.
//  - tie fallback = cold exact brute force in ORIGINAL order (np.argmin
//    semantics by construction), triggered via __any(ballot) — ~never taken.
//
// CRITICAL (round 1/2 lesson): device default -ffp-contract fuses mul into
// sub -> fma, breaking bit-exactness. Keep pragma + opaque asm barriers on
// every product.

constexpr int K     = 128;
constexpr int EPT   = 8;
constexpr int BLOCK = 256;

__global__ __launch_bounds__(BLOCK) void vq_kernel(const float* __restrict__ x,
                                                   const float* __restrict__ w,
                                                   float* __restrict__ out,
                                                   long n, int kk) {
#pragma clang fp contract(off)
    __shared__ float wraw[K];   // original-order codebook (+inf padded)
    __shared__ float sv[K];     // sorted values (ascending, stable by orig idx)

    const int t = threadIdx.x;
    if (t < K) {
        wraw[t] = (t < kk) ? w[t] : __builtin_inff();
        sv[t]   = __builtin_inff();
    }
    __syncthreads();
    if (t < kk) {
        // Stable O(K) rank sort: rank = #{strictly less} + #{equal, earlier}.
        // wraw[j] is wave-uniform per iteration -> broadcast, conflict-free.
        float v = wraw[t];
        int rank = 0;
        for (int j = 0; j < kk; ++j) {
            float u = wraw[j];
            rank += (u < v) || (u == v && j < t);
        }
        sv[rank] = v;
    }
    __syncthreads();

    // Search-tree levels 64/32/16/8 from block-uniform registers (15 values).
    const float m1  = sv[63];
    const float m2a = sv[31],  m2b = sv[95];
    const float m3a = sv[15],  m3b = sv[47],  m3c = sv[79],  m3d = sv[111];
    const float q0  = sv[7],   q1  = sv[23],  q2  = sv[39],  q3  = sv[55];
    const float q4  = sv[71],  q5  = sv[87],  q6  = sv[103], q7  = sv[119];

    long base = ((long)blockIdx.x * BLOCK + t) * (long)EPT;
    if (base + EPT <= n) {
        float4 a = *(const float4*)(x + base);
        float4 b = *(const float4*)(x + base + 4);
        float xs[EPT] = {a.x, a.y, a.z, a.w, b.x, b.y, b.z, b.w};
        float res[EPT];
        int tiebits = 0;
#pragma unroll
        for (int e = 0; e < EPT; ++e) {
            float xv = xs[e];
            float x2 = xv * xv;            // fl(x*x)
            asm volatile("" : "+v"(x2));   // block fma(x,x,·)
            float tx = xv + xv;            // fl(2x), exact

            // lower_bound: pos = #{sv < xv}. Levels 64/32/16/8 in registers.
            int pos = (m1 < xv) ? 64 : 0;
            float m2 = (pos & 64) ? m2b : m2a;
            pos += (m2 < xv) ? 32 : 0;
            float m3lo = (pos & 32) ? m3b : m3a;
            float m3hi = (pos & 32) ? m3d : m3c;
            float m3   = (pos & 64) ? m3hi : m3lo;
            pos += (m3 < xv) ? 16 : 0;
            float u0 = (pos & 16) ? q1 : q0;
            float u1 = (pos & 16) ? q3 : q2;
            float u2 = (pos & 16) ? q5 : q4;
            float u3 = (pos & 16) ? q7 : q6;
            float v0 = (pos & 32) ? u1 : u0;
            float v1 = (pos & 32) ? u3 : u2;
            float m4 = (pos & 64) ? v1 : v0;
            pos += (m4 < xv) ? 8 : 0;
            // Levels 4/2/1 from LDS.
            pos += (sv[pos + 3] < xv) ? 4 : 0;
            pos += (sv[pos + 1] < xv) ? 2 : 0;
            pos += (sv[pos]     < xv) ? 1 : 0;

            // Candidate window [pos-4, pos+3] (margins >=3 around bracket).
            int s = pos - 4;
            s = s < 0 ? 0 : (s > K - 8 ? K - 8 : s);

            float best = __builtin_inff();
            float bw   = 0.0f;
            bool  tie  = false;
#pragma unroll
            for (int c = 0; c < 8; ++c) {
                float wv = sv[s + c];           // b32 window read
                float w2 = wv * wv;             // fl(w*w), same rounding as ref
                asm volatile("" : "+v"(w2));
                float sum  = x2 + w2;           // fl(x^2 + w^2)
                float prod = tx * wv;           // fl(2x * w)
                asm volatile("" : "+v"(prod));  // block fma fusion into sub
                float d = sum - prod;           // fl(sum - prod)
                bool lt = d < best;
                bool eq = (!lt) && (d == best); // exact fp32-dist tie
                tie  = lt ? false : (tie || eq);
                best = lt ? d  : best;
                bw   = lt ? wv : bw;
            }
            tiebits |= tie ? (1 << e) : 0;
            res[e] = bw;
        }

        // Cold path: exact fp32-dist tie inside the window -> redo that
        // element as exact brute force in ORIGINAL order (np.argmin).
        if (__builtin_expect(__any(tiebits != 0), 0)) {
            for (int e = 0; e < EPT; ++e) {
                if (!(tiebits & (1 << e))) continue;
                float xv = xs[e];
                float x2 = xv * xv;
                asm volatile("" : "+v"(x2));
                float tx = xv + xv;
                float best = __builtin_inff(), bwv = 0.0f;
                for (int k = 0; k < kk; ++k) {
                    float wv = wraw[k];
                    float w2 = wv * wv;
                    asm volatile("" : "+v"(w2));
                    float sum  = x2 + w2;
                    float prod = tx * wv;
                    asm volatile("" : "+v"(prod));
                    float d = sum - prod;
                    if (d < best) { best = d; bwv = wv; }  // strict: first wins
                }
                res[e] = bwv;
            }
        }

        *(float4*)(out + base)     = make_float4(res[0], res[1], res[2], res[3]);
        *(float4*)(out + base + 4) = make_float4(res[4], res[5], res[6], res[7]);
    } else {
        // Tail (not hit for N=4,194,304): exact brute force, original order.
        for (long i = base; i < n; ++i) {
            float xv = x[i];
            float x2 = xv * xv;
            asm volatile("" : "+v"(x2));
            float tx = xv + xv;
            float best = __builtin_inff(), bwv = 0.0f;
            for (int k = 0; k < kk; ++k) {
                float wv = wraw[k];
                float w2 = wv * wv;
                asm volatile("" : "+v"(w2));
                float sum  = x2 + w2;
                float prod = tx * wv;
                asm volatile("" : "+v"(prod));
                float d = sum - prod;
                if (d < best) { best = d; bwv = wv; }
            }
            out[i] = bwv;
        }
    }
}

extern "C" void kernel_launch(void* const* d_in, const int* in_sizes, int n_in,
                              void* d_out, int out_size, void* d_ws, size_t ws_size,
                              hipStream_t stream) {
    const float* x = (const float*)d_in[0];
    const float* w = (const float*)d_in[1];
    float* out     = (float*)d_out;
    long n = (long)in_sizes[0];
    int  kk = in_sizes[1] < K ? in_sizes[1] : K;

    long threads_needed = (n + EPT - 1) / EPT;
    long grid = (threads_needed + BLOCK - 1) / BLOCK;
    vq_kernel<<<(int)grid, BLOCK, 0, stream>>>(x, w, out, n, kk);
}